// Round 5
// baseline (352.295 us; speedup 1.0000x reference)
//
#include <hip/hip_runtime.h>

// FGPillarMaxPooling on MI355X (gfx950) — R5: counting-bin rewrite.
//
// R1-R4 evidence: (a) any store path into d_out runs at ~0.93 TB/s (memset,
// float4 stores, NT stores all equal); (b) pillar_fwd's 25.6M atomics run at
// ~226 G/s ~= TCC atomic issue ceiling. The zero+atomicMax design writes the
// 128 MiB output region twice. Fix the algorithm:
//   1) bin_points: 800k atomicAdd into a 4 MiB counter array + bucket of
//      point indices (CAP=16/cell; Poisson(0.76) => overflow ~never, but an
//      overflow list + fixup kernel keeps it exact for any input).
//   2) pool_cells: one 32-lane half-wave per cell, gather <=CAP points,
//      7x32 MLP + running max, ONE plain coalesced store per output line
//      (zeros for empty cells) => 128 MiB written exactly once, no zero pass.
//   3) fixup: atomicMax for overflow-listed points (normally 0).
// Fallback to the R2 zero+atomic design if ws_size is too small (ws_size is
// constant per session, so the branch is graph-safe).

#define GW 512
#define GH 512
#define COUT 32
#define CAP 16
#define MAXOVF 4096

__device__ __forceinline__ void point_geom(float x, float y, int* px_, int* py_,
                                           float* g4, float* g5) {
    // IEEE division to match the reference's floor decisions
    int px = (int)floorf((x - (-51.2f)) / 0.2f);
    int py = (int)floorf((y - (-51.2f)) / 0.2f);
    px = min(max(px, 0), GW - 1);
    py = min(max(py, 0), GH - 1);
    float cx = ((float)px + 0.5f) * 0.2f + (-51.2f);
    float cy = ((float)py + 0.5f) * 0.2f + (-51.2f);
    *px_ = px; *py_ = py;
    *g4 = x - cx; *g5 = y - cy;
}

__device__ __forceinline__ int batch_of(int p, const int* __restrict__ cnt, int B) {
    int b = 0, acc = 0;
    for (int k = 0; k < B; ++k) { acc += cnt[k]; b += (p >= acc) ? 1 : 0; }
    return b;
}

// ---------- pass A: bin points ----------
__global__ __launch_bounds__(256) void bin_points(
    const float* __restrict__ xyz, const int* __restrict__ cnt,
    unsigned int* __restrict__ counters,   // nseg
    unsigned int* __restrict__ ovf_cnt,    // 1
    unsigned int* __restrict__ ovf_list,   // MAXOVF
    unsigned int* __restrict__ bucket,     // nseg*CAP
    int N, int B)
{
    int p = blockIdx.x * 256 + threadIdx.x;
    if (p >= N) return;
    float x = xyz[3 * p + 0];
    float y = xyz[3 * p + 1];
    int b = batch_of(p, cnt, B);
    int px, py; float g4, g5;
    point_geom(x, y, &px, &py, &g4, &g5);
    unsigned int seg = (unsigned int)b * (GH * GW) + (unsigned int)py * GW + (unsigned int)px;
    unsigned int pos = atomicAdd(counters + seg, 1u);
    if (pos < CAP) {
        bucket[(size_t)seg * CAP + pos] = (unsigned int)p;
    } else {
        unsigned int o = atomicAdd(ovf_cnt, 1u);
        if (o < MAXOVF) ovf_list[o] = (unsigned int)p;
    }
}

// ---------- pass B: pool cells, write output once ----------
__global__ __launch_bounds__(256) void pool_cells(
    const float* __restrict__ xyz, const float4* __restrict__ feat,
    const float* __restrict__ W,
    const unsigned int* __restrict__ counters,
    const unsigned int* __restrict__ bucket,
    float* __restrict__ out)
{
    __shared__ float sW[7 * COUT];
    int tid = threadIdx.x;
    if (tid < 7 * COUT) sW[tid] = W[tid];
    __syncthreads();

    int cell = blockIdx.x * 8 + (tid >> 5);   // 8 cells per 256-thread block
    int c = tid & 31;

    int n = (int)counters[cell];
    n = min(n, CAP);

    // decode pillar coords (b not needed for features)
    int px = cell & (GW - 1);
    int py = (cell >> 9) & (GH - 1);
    float cx = ((float)px + 0.5f) * 0.2f + (-51.2f);
    float cy = ((float)py + 0.5f) * 0.2f + (-51.2f);

    float acc = 0.0f;
    for (int i = 0; i < n; ++i) {
        int p = (int)bucket[(size_t)cell * CAP + i];
        float x = xyz[3 * p + 0];
        float y = xyz[3 * p + 1];
        float z = xyz[3 * p + 2];
        float4 f = feat[p];
        float g4 = x - cx;
        float g5 = y - cy;
        float g6 = z + 1.0f;   // cz = -1.0
        float h = f.x * sW[0 * COUT + c]
                + f.y * sW[1 * COUT + c]
                + f.z * sW[2 * COUT + c]
                + f.w * sW[3 * COUT + c]
                + g4  * sW[4 * COUT + c]
                + g5  * sW[5 * COUT + c]
                + g6  * sW[6 * COUT + c];
        acc = fmaxf(acc, fmaxf(h, 0.0f));
    }
    out[(size_t)cell * COUT + c] = acc;
}

// ---------- pass C: overflow fixup (normally a no-op) ----------
__global__ __launch_bounds__(256) void fixup(
    const float* __restrict__ xyz, const int* __restrict__ cnt,
    const float4* __restrict__ feat, const float* __restrict__ W,
    const unsigned int* __restrict__ ovf_cnt,
    const unsigned int* __restrict__ ovf_list,
    unsigned int* __restrict__ out, int B)
{
    __shared__ float sW[7 * COUT];
    int tid = threadIdx.x;
    if (tid < 7 * COUT) sW[tid] = W[tid];
    __syncthreads();

    int n = (int)min(*ovf_cnt, (unsigned int)MAXOVF);
    int c = tid & 31;
    for (int i = tid >> 5; i < n; i += 8) {
        int p = (int)ovf_list[i];
        float x = xyz[3 * p + 0];
        float y = xyz[3 * p + 1];
        float z = xyz[3 * p + 2];
        int b = batch_of(p, cnt, B);
        int px, py; float g4, g5;
        point_geom(x, y, &px, &py, &g4, &g5);
        float g6 = z + 1.0f;
        float4 f = feat[p];
        float h = f.x * sW[0 * COUT + c]
                + f.y * sW[1 * COUT + c]
                + f.z * sW[2 * COUT + c]
                + f.w * sW[3 * COUT + c]
                + g4  * sW[4 * COUT + c]
                + g5  * sW[5 * COUT + c]
                + g6  * sW[6 * COUT + c];
        h = fmaxf(h, 0.0f);
        unsigned int seg = (unsigned int)b * (GH * GW) + (unsigned int)py * GW + (unsigned int)px;
        atomicMax(out + (size_t)seg * COUT + c, __float_as_uint(h));
    }
}

// ---------- fallback (R2 design) ----------
__global__ __launch_bounds__(256) void zero_out4(float4* __restrict__ out, int n4) {
    int stride = gridDim.x * blockDim.x;
    float4 zz = make_float4(0.f, 0.f, 0.f, 0.f);
    for (int i = blockIdx.x * blockDim.x + threadIdx.x; i < n4; i += stride)
        out[i] = zz;
}

__global__ __launch_bounds__(256) void pillar_fwd(
    const float* __restrict__ xyz, const int* __restrict__ cnt,
    const float4* __restrict__ feat, const float* __restrict__ W,
    unsigned int* __restrict__ out, int N, int B)
{
    __shared__ float sW[7 * COUT];
    int tid = threadIdx.x;
    if (tid < 7 * COUT) sW[tid] = W[tid];
    __syncthreads();

    int p = blockIdx.x * 8 + (tid >> 5);
    int c = tid & 31;
    if (p >= N) return;
    float x = xyz[3 * p + 0];
    float y = xyz[3 * p + 1];
    float z = xyz[3 * p + 2];
    int b = batch_of(p, cnt, B);
    int px, py; float g4, g5;
    point_geom(x, y, &px, &py, &g4, &g5);
    float g6 = z + 1.0f;
    float4 f = feat[p];
    float h = f.x * sW[0 * COUT + c]
            + f.y * sW[1 * COUT + c]
            + f.z * sW[2 * COUT + c]
            + f.w * sW[3 * COUT + c]
            + g4  * sW[4 * COUT + c]
            + g5  * sW[5 * COUT + c]
            + g6  * sW[6 * COUT + c];
    h = fmaxf(h, 0.0f);
    unsigned int seg = (unsigned int)b * (GH * GW) + (unsigned int)py * GW + (unsigned int)px;
    atomicMax(out + (size_t)seg * COUT + c, __float_as_uint(h));
}

extern "C" void kernel_launch(void* const* d_in, const int* in_sizes, int n_in,
                              void* d_out, int out_size, void* d_ws, size_t ws_size,
                              hipStream_t stream) {
    const float*  xyz  = (const float*)d_in[0];
    const int*    cnt  = (const int*)d_in[1];
    const float4* feat = (const float4*)d_in[2];
    const float*  W    = (const float*)d_in[3];

    int N = in_sizes[0] / 3;
    int B = in_sizes[1];
    int nseg = out_size / COUT;                 // B*GH*GW

    // ws layout (u32): counters[nseg] | ovf_cnt[1] | ovf_list[MAXOVF] | bucket[nseg*CAP]
    size_t need = (size_t)(nseg + 1 + MAXOVF + (size_t)nseg * CAP) * 4;

    if (ws_size >= need) {
        unsigned int* counters = (unsigned int*)d_ws;
        unsigned int* ovf_cnt  = counters + nseg;
        unsigned int* ovf_list = ovf_cnt + 1;
        unsigned int* bucket   = ovf_list + MAXOVF;

        hipMemsetAsync(d_ws, 0, (size_t)(nseg + 1 + MAXOVF) * 4, stream);

        int gridA = (N + 255) / 256;
        bin_points<<<gridA, 256, 0, stream>>>(xyz, cnt, counters, ovf_cnt, ovf_list,
                                              bucket, N, B);

        int gridB = nseg / 8;                   // nseg = B*512*512, divisible by 8
        pool_cells<<<gridB, 256, 0, stream>>>(xyz, feat, W, counters, bucket,
                                              (float*)d_out);

        fixup<<<1, 256, 0, stream>>>(xyz, cnt, feat, W, ovf_cnt, ovf_list,
                                     (unsigned int*)d_out, B);
    } else {
        // Fallback: zero + atomicMax (R2 design)
        int n4 = out_size / 4;
        zero_out4<<<2048, 256, 0, stream>>>((float4*)d_out, n4);
        int grid = (N + 7) / 8;
        pillar_fwd<<<grid, 256, 0, stream>>>(xyz, cnt, feat, W,
                                             (unsigned int*)d_out, N, B);
    }
}

// Round 6
// 283.168 us; speedup vs baseline: 1.2441x; 1.2441x over previous
//
#include <hip/hip_runtime.h>

// FGPillarMaxPooling on MI355X (gfx950) — R6: payload binning + NT output.
//
// Evidence so far:
//   R1-R4: any store path into the 128 MiB output runs ~0.93-1.3 TB/s;
//          25.6M atomics run at the ~226 G/s atomic ceiling.
//   R5:    index-bucket binning made pool_cells gather xyz/feat per point:
//          FETCH 109 MB (~2 random lines/point), pool 175 us, total 352.
// R6 changes:
//   - bin_points stores the 32 B feature payload (f0..f3,g4,g5,g6) in the
//     bucket: same scattered-line count in bin (1 line/point), but pool now
//     reads only counters + sequential payload (no gather).
//   - pool writes with nontemporal float4 stores (output is write-once,
//     never re-read; don't pollute L2/L3 with 128 MiB).
//   - CAP picked from ws_size (8 -> 4 -> index fallback); overflow list +
//     fixup kernel keeps the result exact for any point distribution.

#define GW 512
#define GH 512
#define COUT 32
#define MAXOVF 65536
#define IDX_CAP 16

typedef float f4 __attribute__((ext_vector_type(4)));

__device__ __forceinline__ int batch_of(int p, const int* __restrict__ cnt, int B) {
    int b = 0, acc = 0;
    for (int k = 0; k < B; ++k) { acc += cnt[k]; b += (p >= acc) ? 1 : 0; }
    return b;
}

__device__ __forceinline__ void point_geom(float x, float y, int* px_, int* py_,
                                           float* g4, float* g5) {
    // IEEE division to match the reference's floor decisions
    int px = (int)floorf((x - (-51.2f)) / 0.2f);
    int py = (int)floorf((y - (-51.2f)) / 0.2f);
    px = min(max(px, 0), GW - 1);
    py = min(max(py, 0), GH - 1);
    float cx = ((float)px + 0.5f) * 0.2f + (-51.2f);
    float cy = ((float)py + 0.5f) * 0.2f + (-51.2f);
    *px_ = px; *py_ = py;
    *g4 = x - cx; *g5 = y - cy;
}

// ---------- pass A: bin points, storing the feature payload ----------
__global__ __launch_bounds__(256) void bin_points_payload(
    const float* __restrict__ xyz, const int* __restrict__ cnt,
    const float4* __restrict__ feat,
    unsigned int* __restrict__ counters,   // nseg
    unsigned int* __restrict__ ovf_cnt,    // 1
    unsigned int* __restrict__ ovf_list,   // MAXOVF
    f4* __restrict__ bucket,               // nseg*cap entries, 2 f4 each
    int N, int B, int cap)
{
    int p = blockIdx.x * 256 + threadIdx.x;
    if (p >= N) return;
    float x = xyz[3 * p + 0];
    float y = xyz[3 * p + 1];
    float z = xyz[3 * p + 2];
    int b = batch_of(p, cnt, B);
    int px, py; float g4, g5;
    point_geom(x, y, &px, &py, &g4, &g5);
    unsigned int seg = (unsigned int)b * (GH * GW) + (unsigned int)py * GW + (unsigned int)px;
    unsigned int pos = atomicAdd(counters + seg, 1u);
    if (pos < (unsigned int)cap) {
        float4 f = feat[p];
        size_t e = ((size_t)seg * cap + pos) * 2;
        f4 v0; v0.x = f.x; v0.y = f.y; v0.z = f.z; v0.w = f.w;
        f4 v1; v1.x = g4;  v1.y = g5;  v1.z = z + 1.0f; v1.w = 0.0f;  // cz=-1.0
        bucket[e]     = v0;
        bucket[e + 1] = v1;
    } else {
        unsigned int o = atomicAdd(ovf_cnt, 1u);
        if (o < MAXOVF) ovf_list[o] = (unsigned int)p;
    }
}

// ---------- pass B: pool cells from payload, NT-write output once ----------
// 256 threads = 32 cells/block; 8 lanes per cell, 4 channels per lane.
__global__ __launch_bounds__(256) void pool_cells_payload(
    const f4* __restrict__ bucket,
    const float* __restrict__ W,
    const unsigned int* __restrict__ counters,
    f4* __restrict__ out, int cap)
{
    __shared__ float sW[7 * COUT];
    int tid = threadIdx.x;
    if (tid < 7 * COUT) sW[tid] = W[tid];
    __syncthreads();

    int cell = blockIdx.x * 32 + (tid >> 3);
    int c4 = (tid & 7) * 4;     // first of this lane's 4 channels

    int n = min((int)counters[cell], cap);

    f4 a = (f4)0.0f;
    if (n > 0) {
        // hoist this lane's 7x4 block of W into registers
        float w[28];
#pragma unroll
        for (int r = 0; r < 7; ++r)
#pragma unroll
            for (int j = 0; j < 4; ++j)
                w[r * 4 + j] = sW[r * COUT + c4 + j];

        const f4* bp = bucket + (size_t)cell * cap * 2;
        for (int i = 0; i < n; ++i) {
            f4 v0 = bp[2 * i];
            f4 v1 = bp[2 * i + 1];
#pragma unroll
            for (int j = 0; j < 4; ++j) {
                float t = v0.x * w[0 * 4 + j]
                        + v0.y * w[1 * 4 + j]
                        + v0.z * w[2 * 4 + j]
                        + v0.w * w[3 * 4 + j]
                        + v1.x * w[4 * 4 + j]
                        + v1.y * w[5 * 4 + j]
                        + v1.z * w[6 * 4 + j];
                t = fmaxf(t, 0.0f);
                a[j] = fmaxf(a[j], t);
            }
        }
    }
    __builtin_nontemporal_store(a, out + (size_t)cell * 8 + (tid & 7));
}

// ---------- pass C: overflow fixup (normally a no-op) ----------
__global__ __launch_bounds__(256) void fixup(
    const float* __restrict__ xyz, const int* __restrict__ cnt,
    const float4* __restrict__ feat, const float* __restrict__ W,
    const unsigned int* __restrict__ ovf_cnt,
    const unsigned int* __restrict__ ovf_list,
    unsigned int* __restrict__ out, int B)
{
    __shared__ float sW[7 * COUT];
    int tid = threadIdx.x;
    if (tid < 7 * COUT) sW[tid] = W[tid];
    __syncthreads();

    int n = (int)min(*ovf_cnt, (unsigned int)MAXOVF);
    int c = tid & 31;
    for (int i = tid >> 5; i < n; i += 8) {
        int p = (int)ovf_list[i];
        float x = xyz[3 * p + 0];
        float y = xyz[3 * p + 1];
        float z = xyz[3 * p + 2];
        int b = batch_of(p, cnt, B);
        int px, py; float g4, g5;
        point_geom(x, y, &px, &py, &g4, &g5);
        float g6 = z + 1.0f;
        float4 f = feat[p];
        float h = f.x * sW[0 * COUT + c]
                + f.y * sW[1 * COUT + c]
                + f.z * sW[2 * COUT + c]
                + f.w * sW[3 * COUT + c]
                + g4  * sW[4 * COUT + c]
                + g5  * sW[5 * COUT + c]
                + g6  * sW[6 * COUT + c];
        h = fmaxf(h, 0.0f);
        unsigned int seg = (unsigned int)b * (GH * GW) + (unsigned int)py * GW + (unsigned int)px;
        atomicMax(out + (size_t)seg * COUT + c, __float_as_uint(h));
    }
}

// ---------- index-bucket fallback (R5 design, NT output store) ----------
__global__ __launch_bounds__(256) void bin_points_idx(
    const float* __restrict__ xyz, const int* __restrict__ cnt,
    unsigned int* __restrict__ counters, unsigned int* __restrict__ ovf_cnt,
    unsigned int* __restrict__ ovf_list, unsigned int* __restrict__ bucket,
    int N, int B)
{
    int p = blockIdx.x * 256 + threadIdx.x;
    if (p >= N) return;
    float x = xyz[3 * p + 0];
    float y = xyz[3 * p + 1];
    int b = batch_of(p, cnt, B);
    int px, py; float g4, g5;
    point_geom(x, y, &px, &py, &g4, &g5);
    unsigned int seg = (unsigned int)b * (GH * GW) + (unsigned int)py * GW + (unsigned int)px;
    unsigned int pos = atomicAdd(counters + seg, 1u);
    if (pos < IDX_CAP) bucket[(size_t)seg * IDX_CAP + pos] = (unsigned int)p;
    else {
        unsigned int o = atomicAdd(ovf_cnt, 1u);
        if (o < MAXOVF) ovf_list[o] = (unsigned int)p;
    }
}

__global__ __launch_bounds__(256) void pool_cells_idx(
    const float* __restrict__ xyz, const float4* __restrict__ feat,
    const float* __restrict__ W,
    const unsigned int* __restrict__ counters,
    const unsigned int* __restrict__ bucket,
    float* __restrict__ out)
{
    __shared__ float sW[7 * COUT];
    int tid = threadIdx.x;
    if (tid < 7 * COUT) sW[tid] = W[tid];
    __syncthreads();

    int cell = blockIdx.x * 8 + (tid >> 5);
    int c = tid & 31;
    int n = min((int)counters[cell], IDX_CAP);

    int px = cell & (GW - 1);
    int py = (cell >> 9) & (GH - 1);
    float cx = ((float)px + 0.5f) * 0.2f + (-51.2f);
    float cy = ((float)py + 0.5f) * 0.2f + (-51.2f);

    float acc = 0.0f;
    for (int i = 0; i < n; ++i) {
        int p = (int)bucket[(size_t)cell * IDX_CAP + i];
        float x = xyz[3 * p + 0];
        float y = xyz[3 * p + 1];
        float z = xyz[3 * p + 2];
        float4 f = feat[p];
        float g4 = x - cx, g5 = y - cy, g6 = z + 1.0f;
        float h = f.x * sW[0 * COUT + c]
                + f.y * sW[1 * COUT + c]
                + f.z * sW[2 * COUT + c]
                + f.w * sW[3 * COUT + c]
                + g4  * sW[4 * COUT + c]
                + g5  * sW[5 * COUT + c]
                + g6  * sW[6 * COUT + c];
        acc = fmaxf(acc, fmaxf(h, 0.0f));
    }
    __builtin_nontemporal_store(acc, out + (size_t)cell * COUT + c);
}

extern "C" void kernel_launch(void* const* d_in, const int* in_sizes, int n_in,
                              void* d_out, int out_size, void* d_ws, size_t ws_size,
                              hipStream_t stream) {
    const float*  xyz  = (const float*)d_in[0];
    const int*    cnt  = (const int*)d_in[1];
    const float4* feat = (const float4*)d_in[2];
    const float*  W    = (const float*)d_in[3];

    int N = in_sizes[0] / 3;
    int B = in_sizes[1];
    int nseg = out_size / COUT;                 // B*GH*GW = 1,048,576
    size_t tailBytes = (size_t)(nseg + 1 + MAXOVF) * 4;  // counters|ovf_cnt|ovf_list

    // choose payload CAP by available workspace (ws_size constant -> graph-safe)
    int cap = 0;
    if (ws_size >= (size_t)nseg * 8 * 32 + tailBytes)      cap = 8;
    else if (ws_size >= (size_t)nseg * 4 * 32 + tailBytes) cap = 4;

    int gridA = (N + 255) / 256;

    if (cap) {
        // layout: bucket (16B-aligned, at 0) | counters | ovf_cnt | ovf_list
        size_t bucketBytes = (size_t)nseg * cap * 32;
        f4*           bucket   = (f4*)d_ws;
        unsigned int* counters = (unsigned int*)((char*)d_ws + bucketBytes);
        unsigned int* ovf_cnt  = counters + nseg;
        unsigned int* ovf_list = ovf_cnt + 1;

        hipMemsetAsync(counters, 0, (size_t)(nseg + 1) * 4, stream);

        bin_points_payload<<<gridA, 256, 0, stream>>>(xyz, cnt, feat, counters,
                                                      ovf_cnt, ovf_list, bucket,
                                                      N, B, cap);
        pool_cells_payload<<<nseg / 32, 256, 0, stream>>>(bucket, W, counters,
                                                          (f4*)d_out, cap);
        fixup<<<1, 256, 0, stream>>>(xyz, cnt, feat, W, ovf_cnt, ovf_list,
                                     (unsigned int*)d_out, B);
    } else {
        // index-bucket fallback: counters | ovf_cnt | ovf_list | bucket
        unsigned int* counters = (unsigned int*)d_ws;
        unsigned int* ovf_cnt  = counters + nseg;
        unsigned int* ovf_list = ovf_cnt + 1;
        unsigned int* bucket   = ovf_list + MAXOVF;

        hipMemsetAsync(counters, 0, (size_t)(nseg + 1) * 4, stream);

        bin_points_idx<<<gridA, 256, 0, stream>>>(xyz, cnt, counters, ovf_cnt,
                                                  ovf_list, bucket, N, B);
        pool_cells_idx<<<nseg / 8, 256, 0, stream>>>(xyz, feat, W, counters,
                                                     bucket, (float*)d_out);
        fixup<<<1, 256, 0, stream>>>(xyz, cnt, feat, W, ovf_cnt, ovf_list,
                                     (unsigned int*)d_out, B);
    }
}